// Round 1
// baseline (753.201 us; speedup 1.0000x reference)
//
#include <hip/hip_runtime.h>
#include <stdint.h>

// Problem constants (static per reference)
#define S_TOK   8192
#define MODEL_D 1024
#define N_EXP   64
#define CAP     128         // max(ceil(8192/64*1.0), 8)
#define SHIFT   4096        // int(S * 0.5)
#define SLAB    (N_EXP * CAP)   // 8192 floats per token in combine/dispatch
#define CDSIZE  ((size_t)S_TOK * SLAB)  // 67108864

// d_out layout (float32): [l_aux(1) | combine(CDSIZE) | dispatch(CDSIZE) | exp_counts(64) | unrouted(1)]

// ws offsets (bytes, all 16B-aligned)
#define OFF_EXPERT   0          // int[8192]
#define OFF_GATE     32768      // float[8192]  gate value at argmax (=1/Z)
#define OFF_KEY      65536      // uint[8192]   sortable importance key
#define OFF_KEY2     98304      // uint[8192]   (expert<<13)|pos
#define OFF_LOC      131072     // int[8192]
#define OFF_MEPART   163840     // float[256][64] per-block gate column sums
#define OFF_HIST     229376     // int[256][64]   per-block argmax histograms
#define OFF_DROP     294912     // int[256]       per-block dropped-token counts
#define OFF_WGT      295936     // float[1024][64] transposed gate weights

__device__ __forceinline__ unsigned f2key(float f) {
    // monotonic float->uint transform (ascending float == ascending uint)
    unsigned b = __float_as_uint(f);
    return (b & 0x80000000u) ? ~b : (b | 0x80000000u);
}

// K0: transpose wg [64][1024] -> wgT [1024][64] so the GEMM's weight loads coalesce.
__global__ __launch_bounds__(256) void k0_transpose(const float* __restrict__ wg,
                                                    float* __restrict__ wgT) {
    int id0 = blockIdx.x * 256 + threadIdx.x;
#pragma unroll
    for (int i = 0; i < 4; ++i) {
        int id = id0 + i * 16384;            // 64*1024 = 65536 total
        int e = id >> 10;
        int d = id & 1023;
        wgT[d * 64 + e] = wg[id];
    }
}

// K1: gate GEMM + softmax + argmax + importance key + per-block me/hist partials.
// 256 blocks x 256 threads; each wave handles 8 tokens, lane = expert.
__global__ __launch_bounds__(256) void k1_gemm_softmax(
    const float* __restrict__ x, const float* __restrict__ wgT,
    int* __restrict__ expert_id, float* __restrict__ gate1,
    unsigned* __restrict__ keys, float* __restrict__ me_part,
    int* __restrict__ hist_part)
{
    __shared__ float lg[32][65];     // logits tile, padded (row stride 65 -> conflict-free)
    __shared__ float mrow[32], zrow[32];
    __shared__ int   exrow[32];
    __shared__ int   hist[64];
    __shared__ float mep[4][64];

    const int tid  = threadIdx.x;
    const int lane = tid & 63;                                   // expert index
    const int wave = __builtin_amdgcn_readfirstlane(tid >> 6);   // uniform -> scalar x loads
    const int tokBase = blockIdx.x * 32 + wave * 8;

    float acc[8] = {0.f,0.f,0.f,0.f,0.f,0.f,0.f,0.f};
    const float* xrow = x + (size_t)tokBase * MODEL_D;

    for (int d = 0; d < MODEL_D; d += 4) {
        float w0 = wgT[(d + 0) * 64 + lane];
        float w1 = wgT[(d + 1) * 64 + lane];
        float w2 = wgT[(d + 2) * 64 + lane];
        float w3 = wgT[(d + 3) * 64 + lane];
#pragma unroll
        for (int t = 0; t < 8; ++t) {
            const float* xr = xrow + t * MODEL_D + d;  // wave-uniform address -> s_load
            acc[t] = fmaf(xr[0], w0, acc[t]);
            acc[t] = fmaf(xr[1], w1, acc[t]);
            acc[t] = fmaf(xr[2], w2, acc[t]);
            acc[t] = fmaf(xr[3], w3, acc[t]);
        }
    }
#pragma unroll
    for (int t = 0; t < 8; ++t) lg[wave * 8 + t][lane] = acc[t];
    __syncthreads();

    if (tid < 64) hist[tid] = 0;
    if (tid < 32) {
        const int t = tid;
        float m = lg[t][0]; int am = 0;
        for (int e = 1; e < 64; ++e) {
            float v = lg[t][e];
            if (v > m) { m = v; am = e; }   // strict > : first-occurrence argmax (jnp semantics)
        }
        float z = 0.f;
        for (int e = 0; e < 64; ++e) z += expf(lg[t][e] - m);
        float rz = 1.0f / z;                // = max gate value
        mrow[t] = m; zrow[t] = rz; exrow[t] = am;
        int sG = blockIdx.x * 32 + t;
        expert_id[sG] = am;
        gate1[sG] = rz;
        keys[sG] = f2key(-rz);              // importance = -maxgate, ascending sort key
    }
    __syncthreads();

    if (tid < 32) atomicAdd(&hist[exrow[tid]], 1);
    {   // me column partial sums: thread (e = tid&63, tg = tid>>6)
        const int e = tid & 63, tg = tid >> 6;
        float p = 0.f;
        for (int t = tg; t < 32; t += 4) p += expf(lg[t][e] - mrow[t]) * zrow[t];
        mep[tg][e] = p;
    }
    __syncthreads();

    if (tid < 64) {
        me_part[blockIdx.x * 64 + tid] = mep[0][tid] + mep[1][tid] + mep[2][tid] + mep[3][tid];
        hist_part[blockIdx.x * 64 + tid] = hist[tid];
    }
}

// K2: global rank by (importance key, index), then pos = (rank+SHIFT)&(S-1),
// emit packed key2 = (expert<<13)|pos. O(S^2) count; all keys staged in LDS.
__global__ __launch_bounds__(256) void k2_rank(const unsigned* __restrict__ keys,
                                               const int* __restrict__ expert_id,
                                               unsigned* __restrict__ key2)
{
    __shared__ uint4 k4[2048];   // all 8192 keys, 32 KB
    const int tid = threadIdx.x;
    const uint4* kg = (const uint4*)keys;
    for (int i = tid; i < 2048; i += 256) k4[i] = kg[i];
    __syncthreads();

    const int sl = tid >> 3, part = tid & 7;   // 32 tokens/block, 8 scan-threads/token
    const int sG = blockIdx.x * 32 + sl;
    const unsigned myk = ((const unsigned*)k4)[sG];
    int cnt = 0;
    const int qbase = part * 256;
    for (int q = 0; q < 256; ++q) {
        uint4 v = k4[qbase + q];
        int j = (qbase + q) * 4;
        cnt += (v.x < myk) || (v.x == myk && (j + 0) < sG);
        cnt += (v.y < myk) || (v.y == myk && (j + 1) < sG);
        cnt += (v.z < myk) || (v.z == myk && (j + 2) < sG);
        cnt += (v.w < myk) || (v.w == myk && (j + 3) < sG);
    }
    cnt += __shfl_down(cnt, 4);
    cnt += __shfl_down(cnt, 2);
    cnt += __shfl_down(cnt, 1);
    if (part == 0) {
        int pos = (cnt + SHIFT) & (S_TOK - 1);
        key2[sG] = ((unsigned)expert_id[sG] << 13) | (unsigned)pos;
    }
}

// K3: loc = rank of token within its expert by pos = #{t : key2 in [expert<<13, mykey2)}.
__global__ __launch_bounds__(256) void k3_loc(const unsigned* __restrict__ key2,
                                              int* __restrict__ loc,
                                              int* __restrict__ drop_part)
{
    __shared__ uint4 k4[2048];
    __shared__ int dropc;
    const int tid = threadIdx.x;
    if (tid == 0) dropc = 0;
    const uint4* kg = (const uint4*)key2;
    for (int i = tid; i < 2048; i += 256) k4[i] = kg[i];
    __syncthreads();

    const int sl = tid >> 3, part = tid & 7;
    const int sG = blockIdx.x * 32 + sl;
    const unsigned myk = ((const unsigned*)k4)[sG];
    const unsigned lo = myk & ~8191u;   // expert<<13
    int cnt = 0;
    const int qbase = part * 256;
    for (int q = 0; q < 256; ++q) {
        uint4 v = k4[qbase + q];
        cnt += (v.x >= lo) && (v.x < myk);
        cnt += (v.y >= lo) && (v.y < myk);
        cnt += (v.z >= lo) && (v.z < myk);
        cnt += (v.w >= lo) && (v.w < myk);
    }
    cnt += __shfl_down(cnt, 4);
    cnt += __shfl_down(cnt, 2);
    cnt += __shfl_down(cnt, 1);
    if (part == 0) {
        loc[sG] = cnt;
        if (cnt >= CAP) atomicAdd(&dropc, 1);
    }
    __syncthreads();
    if (tid == 0) drop_part[blockIdx.x] = dropc;
}

// K4: fused zero-fill + one-hot scatter of combine/dispatch (512 MB store stream),
// plus one extra block for the scalar outputs (l_aux, exp_counts, unrouted rate).
__global__ __launch_bounds__(256) void k4_write(const int* __restrict__ expert_id,
                                                const float* __restrict__ gate1,
                                                const int* __restrict__ loc,
                                                const float* __restrict__ me_part,
                                                const int* __restrict__ hist_part,
                                                const int* __restrict__ drop_part,
                                                float* __restrict__ out)
{
    const int b = blockIdx.x;
    if (b < S_TOK) {
        const int es = expert_id[b];
        const int lc = loc[b];
        const float g = gate1[b];
        const bool kept = (lc < CAP);
        const int hot = es * CAP + lc;           // valid only if kept
        float* outC = out + 1 + (size_t)b * SLAB;
        float* outD = outC + CDSIZE;
        for (int i = threadIdx.x; i < SLAB; i += 256) {
            bool is = kept && (i == hot);
            outC[i] = is ? g : 0.0f;
            outD[i] = is ? 1.0f : 0.0f;
        }
    } else {
        __shared__ float contrib[64];
        const int tid = threadIdx.x;
        if (tid < 64) {
            float ms = 0.f; int hs = 0;
            for (int p = 0; p < 256; ++p) {
                ms += me_part[p * 64 + tid];
                hs += hist_part[p * 64 + tid];
            }
            out[1 + 2 * CDSIZE + tid] = (float)hs;                      // exp_counts
            contrib[tid] = (ms * (1.0f / S_TOK)) * ((float)hs * (1.0f / S_TOK));
        }
        __syncthreads();
        if (tid == 0) {
            float sum = 0.f;
            for (int e = 0; e < 64; ++e) sum += contrib[e];
            out[0] = sum * (float)N_EXP * 0.01f;                        // l_aux
            int dr = 0;
            for (int p = 0; p < 256; ++p) dr += drop_part[p];
            out[1 + 2 * CDSIZE + 64] = (float)dr * (1.0f / S_TOK);      // unrouted rate
        }
    }
}

extern "C" void kernel_launch(void* const* d_in, const int* in_sizes, int n_in,
                              void* d_out, int out_size, void* d_ws, size_t ws_size,
                              hipStream_t stream) {
    (void)in_sizes; (void)n_in; (void)out_size; (void)ws_size;
    const float* x  = (const float*)d_in[0];
    const float* wg = (const float*)d_in[1];
    float* out = (float*)d_out;
    char* ws = (char*)d_ws;

    int*      expert_id = (int*)(ws + OFF_EXPERT);
    float*    gate1     = (float*)(ws + OFF_GATE);
    unsigned* keys      = (unsigned*)(ws + OFF_KEY);
    unsigned* key2      = (unsigned*)(ws + OFF_KEY2);
    int*      loc       = (int*)(ws + OFF_LOC);
    float*    me_part   = (float*)(ws + OFF_MEPART);
    int*      hist_part = (int*)(ws + OFF_HIST);
    int*      drop_part = (int*)(ws + OFF_DROP);
    float*    wgT       = (float*)(ws + OFF_WGT);

    hipLaunchKernelGGL(k0_transpose,    dim3(64),   dim3(256), 0, stream, wg, wgT);
    hipLaunchKernelGGL(k1_gemm_softmax, dim3(256),  dim3(256), 0, stream, x, wgT,
                       expert_id, gate1, keys, me_part, hist_part);
    hipLaunchKernelGGL(k2_rank,         dim3(256),  dim3(256), 0, stream, keys, expert_id, key2);
    hipLaunchKernelGGL(k3_loc,          dim3(256),  dim3(256), 0, stream, key2, loc, drop_part);
    hipLaunchKernelGGL(k4_write,        dim3(8193), dim3(256), 0, stream,
                       expert_id, gate1, loc, me_part, hist_part, drop_part, out);
}